// Round 8
// baseline (148.831 us; speedup 1.0000x reference)
//
#include <hip/hip_runtime.h>
#include <math.h>

// Problem constants
#define LQ 1024
#define EQ 512
#define BQ 32
#define MQ 64

static constexpr int BCHUNK = LQ * EQ;   // 524288 floats per b-slice of d_out
// d_out overlay (per b-slice of 524288 floats), phase by phase:
//  k_trig:   Tm bf16 A-frags in slice0 floats [0, 131072)  (hi: [0,65536), lo: [65536,131072))
//  k_dft3:   reads q + Tm-frags; writes SPLITX bf16 arrays 0..3 (sx_ptr) in
//            slices z=0..7 at [z][262144, 524288)  (disjoint from Tm-frags)
//  k_modes6: Opart[hs][c][i] hs=0..3 at b*BCHUNK + hs*65536  [0,262144)
//            (overwrites Tm-frags -- dft3 already done; reads SPLITX + W only)
//  k_inv3:   y[l][i] overwrites slice. Each block reads ONLY its own i-columns
//            of the 4 partials (staged to LDS before any write -> WAR-safe).

typedef short short8 __attribute__((ext_vector_type(8)));
typedef float f32x4 __attribute__((ext_vector_type(4)));
typedef unsigned short ushort_t;

union FragI { int i[4]; int4 v; short8 s; };

// SPLITX: 4 bf16 arrays, fragment-friendly layout [m(64)][hblk(16)][b(32)][hh(32)]
// arr: 0=xrHi 1=xrLo 2=xiHi 3=xiLo.  (negated-imag arrays removed: the W-side
// is negated instead -- bf16 sign flip is exact, products bitwise identical.)
// Flat bf16 index G = arr*2^20 + m*16384 + (h/32)*1024 + b*32 + (h%32),
// mapped into 1MB-float zones: zone z = G>>19 lives at slice z offset 262144.
__device__ inline char* sx_ptr(float* dout, int arr, int m, int b, int h) {
    unsigned G = ((unsigned)arr << 20) + ((unsigned)m << 14) +
                 ((unsigned)(h >> 5) << 10) + ((unsigned)b << 5) + (unsigned)(h & 31);
    unsigned z = G >> 19, w = G & 524287u;
    return (char*)(dout + (size_t)z * BCHUNK + 262144) + (size_t)w * 2;
}

// split two fp32 into packed bf16 pairs (truncation; lo captures the residual)
__device__ inline void split2(float a, float b, unsigned& hi, unsigned& lo) {
    unsigned ua = __float_as_uint(a), ub = __float_as_uint(b);
    unsigned ha = ua & 0xFFFF0000u, hb = ub & 0xFFFF0000u;
    hi = (ua >> 16) | hb;
    float la = a - __uint_as_float(ha);
    float lb = b - __uint_as_float(hb);
    lo = (__float_as_uint(la) >> 16) | (__float_as_uint(lb) & 0xFFFF0000u);
}

// single-value truncation split (same numerics as split2, one element)
__device__ inline void split1(float x, ushort_t& hi, ushort_t& lo) {
    unsigned u = __float_as_uint(x);
    hi = (ushort_t)(u >> 16);
    float r = x - __uint_as_float(u & 0xFFFF0000u);
    lo = (ushort_t)(__float_as_uint(r) >> 16);
}

// ---------------- kernel 0: trig tables ----------------
// BFhi/BFlo (ws): irfft basis Bas[l][c] in MFMA A-frag layout (round-6 layout).
// THs/TLs (d_out slice0): forward-DFT matrix Tm[mc][l] as bf16 hi/lo A-frags.
__global__ __launch_bounds__(256) void k_trig(unsigned* __restrict__ BFhi,
                                              unsigned* __restrict__ BFlo,
                                              float* __restrict__ dout) {
    int idx = blockIdx.x * 256 + threadIdx.x;   // 0..65535 = l*64+m
    int l = idx >> 6, m = idx & 63;
    int tt = (l * m) & (LQ - 1);
    float ang = (float)tt * 6.135923151542565e-03f;  // 2*pi/1024
    float s, c;
    sincosf(ang, &s, &c);
    // irfft basis fragments (ws)
    float coef = (m == 0 ? 1.0f : 2.0f) * (1.0f / (float)LQ);
    float b0 = coef * c;
    float b1 = (m == 0) ? 0.0f : (-2.0f / (float)LQ) * s;
    unsigned hi, lo;
    split2(b0, b1, hi, lo);
    {
        int lt = l >> 4, kb = m >> 4, kgb = (m & 15) >> 2;
        int lane = kgb * 16 + (l & 15);
        int u = lt * 1024 + kb * 256 + lane * 4 + (m & 3);
        BFhi[u] = hi;
        BFlo[u] = lo;
    }
    // forward-DFT fragments (d_out slice0)
    ushort_t* THs = (ushort_t*)dout;
    ushort_t* TLs = (ushort_t*)(dout + 65536);
    int ks = l >> 5, kg = (l >> 3) & 3, j = l & 7;
    int mt = m >> 3;
    int lane0 = kg * 16 + 2 * (m & 7);          // row mc=2m
    ushort_t ch, cl, sh, sl;
    split1(c, ch, cl);                          // cos
    split1(-s, sh, sl);                         // -sin
    int u0 = ((ks * 8 + mt) * 64 + lane0) * 8 + j;
    THs[u0] = ch;  TLs[u0] = cl;
    THs[u0 + 8] = sh;  TLs[u0 + 8] = sl;        // row mc=2m+1 (lane0+1)
}

// ---------------- kernel 1: truncated DFT via MFMA, fused SPLITX output -----
// Per b: D[mc][h] = sum_l Tm[mc][l] * q[l][h]; M=mc(128), K=l(1024), N=h(512).
__global__ __launch_bounds__(512) void k_dft3(const float* __restrict__ q,
                                              float* __restrict__ dout) {
    __shared__ float qs[64][34];
    const int t    = threadIdx.x;
    const int wave = t >> 6;
    const int lane = t & 63;
    const int a    = wave & 3;
    const int ht   = wave >> 2;
    const int b    = blockIdx.x >> 4;
    const int hg   = blockIdx.x & 15;
    const int hbase = hg * 32;
    const int col  = lane & 15;
    const int kg   = lane >> 4;
    const float* qb = q + (size_t)b * BCHUNK;
    const int4* TH4 = (const int4*)dout;
    const int4* TL4 = (const int4*)(dout + 65536);

    f32x4 acc[2] = {{0.f, 0.f, 0.f, 0.f}, {0.f, 0.f, 0.f, 0.f}};
    float2 st2[2];
#define LOADQ(CC)                                                             \
    {                                                                         \
        int l0_ = (CC) * 64;                                                  \
        _Pragma("unroll")                                                     \
        for (int r = 0; r < 2; ++r) {                                         \
            int e = r * 512 + t;                                              \
            int lp = e >> 4, hc = (e & 15) * 2;                               \
            st2[r] = *(const float2*)&qb[(size_t)(l0_ + lp) * EQ + hbase + hc]; \
        }                                                                     \
    }

    LOADQ(0);
#define MM(A, B, C) C = __builtin_amdgcn_mfma_f32_16x16x32_bf16(A, B, C, 0, 0, 0)
    for (int cchunk = 0; cchunk < 16; ++cchunk) {
#pragma unroll
        for (int r = 0; r < 2; ++r) {           // drain staging regs -> LDS
            int e = r * 512 + t;
            int lp = e >> 4, hc = (e & 15) * 2;
            *(float2*)&qs[lp][hc] = st2[r];
        }
        __syncthreads();
        if (cchunk < 15) LOADQ(cchunk + 1);     // prefetch next chunk
#pragma unroll
        for (int ksl = 0; ksl < 2; ++ksl) {
            const int ks = cchunk * 2 + ksl;
            // B-frag: q[l][h] hi/lo
            float v[8];
#pragma unroll
            for (int j = 0; j < 8; ++j)
                v[j] = qs[ksl * 32 + kg * 8 + j][ht * 16 + col];
            FragI bhiF, bloF;
#pragma unroll
            for (int k = 0; k < 4; ++k) {
                unsigned h_, l_;
                split2(v[2 * k], v[2 * k + 1], h_, l_);
                bhiF.i[k] = (int)h_;
                bloF.i[k] = (int)l_;
            }
            // A-frags + MFMA
#pragma unroll
            for (int ti = 0; ti < 2; ++ti) {
                int mt = 2 * a + ti;
                FragI ah, al;
                ah.v = TH4[(ks * 8 + mt) * 64 + lane];
                al.v = TL4[(ks * 8 + mt) * 64 + lane];
                MM(ah.s, bhiF.s, acc[ti]);
                MM(ah.s, bloF.s, acc[ti]);
                MM(al.s, bhiF.s, acc[ti]);
            }
        }
        __syncthreads();
    }
#undef MM
#undef LOADQ
    // epilogue: split accumulators into SPLITX arrays 0..3
    const int h = hbase + ht * 16 + col;
#pragma unroll
    for (int ti = 0; ti < 2; ++ti) {
        int mt = 2 * a + ti;
        int mA = mt * 8 + kg * 2;
#pragma unroll
        for (int mi = 0; mi < 2; ++mi) {
            float xr = acc[ti][2 * mi];
            float xi = acc[ti][2 * mi + 1];
            ushort_t rh, rl, ih_, il_;
            split1(xr, rh, rl);
            split1(xi, ih_, il_);
            int m = mA + mi;
            *(ushort_t*)sx_ptr(dout, 0, m, b, h) = rh;
            *(ushort_t*)sx_ptr(dout, 1, m, b, h) = rl;
            *(ushort_t*)sx_ptr(dout, 2, m, b, h) = ih_;
            *(ushort_t*)sx_ptr(dout, 3, m, b, h) = il_;
        }
    }
}

// ---------------- kernel 2: per-mode complex GEMM, v7 ----------------
// Opart[hs][b][2m+ri][i] = sum_{h in hs quarter} X[b][h][m] * W[h][i][m]
// logical blk 512 = hs(4) x mc(4: 16 m) x it(32: 16 i); physical blockIdx is
// XCD-swizzled: blk = (p%8)*64 + p/8, so each XCD hosts 2 complete (hs,mc)
// groups -> their SPLITX chunks (~1MB) stay resident in that XCD's 4MB L2
// (X was previously re-read 32x from L3 = the round-7 bottleneck).
// All 512 blocks co-resident (2/CU). out_r's Wi term uses sign-negated W
// A-frags (exact) instead of the removed negated-X arrays.
__global__ __launch_bounds__(512) void k_modes6(const float* __restrict__ wreal,
                                                const float* __restrict__ wimag,
                                                float* __restrict__ dout) {
    __shared__ float Wlds[2 * 32 * 16 * 18];   // 73728 B
    const int t    = threadIdx.x;
    const int wave = t >> 6;
    const int lane = t & 63;
    const int p    = blockIdx.x;
    const int blk  = (p & 7) * 64 + (p >> 3);  // XCD swizzle (bijective, 512%8==0)
    const int hs   = blk >> 7;           // 0..3
    const int mc   = (blk >> 5) & 3;
    const int it   = blk & 31;
    const int i0   = it * 16;
    const int m0   = mc * 16;
    const int col  = lane & 15;          // A row (i) / B col (b)
    const int kg   = lane >> 4;          // k-group
    const int hbase = hs * 128;

    const char* xp0 = sx_ptr(dout, 0, m0 + 2 * wave, col, hbase + kg * 8);

    f32x4 zero4 = {0.f, 0.f, 0.f, 0.f};
    f32x4 acc[2][2][2];                  // [mi][part][nt]
#pragma unroll
    for (int a = 0; a < 2; ++a)
#pragma unroll
        for (int bq = 0; bq < 2; ++bq)
#pragma unroll
            for (int c = 0; c < 2; ++c) acc[a][bq][c] = zero4;

    float2 st[16];                       // staging regs (double-buffer)
#define LOADK(KK)                                                             \
    {                                                                         \
        int h0_ = hbase + (KK) * 32;                                          \
        _Pragma("unroll")                                                     \
        for (int r = 0; r < 16; ++r) {                                        \
            int e = r * 512 + t;                                              \
            int m2 = e & 7, ii = (e >> 3) & 15, hh = (e >> 7) & 31;           \
            const float* src = (e >> 12) ? wimag : wreal;                     \
            st[r] = *(const float2*)&src[(size_t)(h0_ + hh) * 32768 +         \
                                         (size_t)(i0 + ii) * 64 + m0 + 2 * m2]; \
        }                                                                     \
    }

    LOADK(0);
    for (int kk = 0; kk < 4; ++kk) {
#pragma unroll
        for (int r = 0; r < 16; ++r) {
            int e = r * 512 + t;
            int m2 = e & 7, ii = (e >> 3) & 15, hh = (e >> 7) & 31;
            int part = e >> 12;
            *(float2*)&Wlds[(((part * 32 + hh) * 16) + ii) * 18 + 2 * m2] = st[r];
        }
        __syncthreads();
        if (kk < 3) LOADK(kk + 1);       // prefetch next chunk under compute
#pragma unroll
        for (int mi = 0; mi < 2; ++mi) {
            const int mloc = 2 * wave + mi;
            short8 aW[2][2];             // [part][prec]: 0=Wr 1=Wi
            short8 nW[2];                // negated Wi hi/lo (exact sign flip)
#pragma unroll
            for (int part = 0; part < 2; ++part) {
                float v[8];
#pragma unroll
                for (int j = 0; j < 8; ++j)
                    v[j] = Wlds[((part * 32 + kg * 8 + j) * 16 + col) * 18 + mloc];
                FragI hiF, loF;
#pragma unroll
                for (int k = 0; k < 4; ++k) {
                    unsigned h, l;
                    split2(v[2 * k], v[2 * k + 1], h, l);
                    hiF.i[k] = (int)h;
                    loF.i[k] = (int)l;
                }
                aW[part][0] = hiF.s;
                aW[part][1] = loF.s;
                if (part == 1) {
                    FragI nh, nl;
#pragma unroll
                    for (int k = 0; k < 4; ++k) {
                        nh.i[k] = hiF.i[k] ^ 0x80008000;
                        nl.i[k] = loF.i[k] ^ 0x80008000;
                    }
                    nW[0] = nh.s;
                    nW[1] = nl.s;
                }
            }
            const char* xpm = xp0 + (size_t)mi * 32768 + (size_t)kk * 2048;
#define MM(A, B, C) C = __builtin_amdgcn_mfma_f32_16x16x32_bf16(A, B, C, 0, 0, 0)
#pragma unroll
            for (int nt = 0; nt < 2; ++nt) {
                short8 bX[4];
#pragma unroll
                for (int arr = 0; arr < 4; ++arr) {
                    FragI f;
                    f.v = *(const int4*)(xpm + (size_t)arr * 4194304 +
                                         (size_t)nt * 1024);
                    bX[arr] = f.s;
                }
                // out_r = WrHi*xrHi + WrHi*xrLo + WrLo*xrHi
                //       + (-WiHi)*xiHi + (-WiHi)*xiLo + (-WiLo)*xiHi
                MM(aW[0][0], bX[0], acc[mi][0][nt]);
                MM(aW[0][0], bX[1], acc[mi][0][nt]);
                MM(aW[0][1], bX[0], acc[mi][0][nt]);
                MM(nW[0],    bX[2], acc[mi][0][nt]);
                MM(nW[0],    bX[3], acc[mi][0][nt]);
                MM(nW[1],    bX[2], acc[mi][0][nt]);
                // out_i = WrHi*xiHi + WrHi*xiLo + WrLo*xiHi
                //       + WiHi*xrHi + WiHi*xrLo + WiLo*xrHi
                MM(aW[0][0], bX[2], acc[mi][1][nt]);
                MM(aW[0][0], bX[3], acc[mi][1][nt]);
                MM(aW[0][1], bX[2], acc[mi][1][nt]);
                MM(aW[1][0], bX[0], acc[mi][1][nt]);
                MM(aW[1][0], bX[1], acc[mi][1][nt]);
                MM(aW[1][1], bX[0], acc[mi][1][nt]);
            }
#undef MM
        }
        __syncthreads();
    }
#undef LOADK
#pragma unroll
    for (int mi = 0; mi < 2; ++mi)
#pragma unroll
        for (int part = 0; part < 2; ++part)
#pragma unroll
            for (int nt = 0; nt < 2; ++nt) {
                int bb = nt * 16 + col;
                int c = 2 * (m0 + 2 * wave + mi) + part;
                f32x4 vv = acc[mi][part][nt];
                float4 o = make_float4(vv.x, vv.y, vv.z, vv.w);
                *(float4*)&dout[(size_t)bb * BCHUNK + (size_t)hs * 65536 +
                                (size_t)c * EQ + i0 + kg * 4] = o;
            }
}

// ---------------- kernel 3: truncated irfft via MFMA (unchanged) ----------
__global__ __launch_bounds__(256) void k_inv3(const unsigned* __restrict__ BFhi,
                                              const unsigned* __restrict__ BFlo,
                                              float* __restrict__ dout) {
    __shared__ unsigned Bf[4096];   // [hilo(2)][nt(2)][kb(4)][lane(64)][4] 16KB
    const int t    = threadIdx.x;
    const int wave = t >> 6;
    const int lane = t & 63;
    const int b    = blockIdx.x >> 4;
    const int it   = blockIdx.x & 15;
    const int i0   = it * 32;
    float* base = dout + (size_t)b * BCHUNK;

#pragma unroll
    for (int r = 0; r < 8; ++r) {
        int idx = r * 256 + t;               // 2048 = 64 c-pairs x 32 i
        int il = idx & 31, cp = idx >> 5;
        int c0 = 2 * cp;
        const float* p0 = base + (size_t)c0 * EQ + i0 + il;
        float s0 = p0[0] + p0[65536] + p0[2 * 65536] + p0[3 * 65536];
        const float* p1 = p0 + EQ;
        float s1 = p1[0] + p1[65536] + p1[2 * 65536] + p1[3 * 65536];
        unsigned hi, lo;
        split2(s0, s1, hi, lo);
        int nt = il >> 4, i_loc = il & 15;
        int kb = c0 >> 5, kg = (c0 & 31) >> 3, jp = (c0 & 7) >> 1;
        int u = (nt * 4 + kb) * 256 + (kg * 16 + i_loc) * 4 + jp;
        Bf[u] = hi;
        Bf[2048 + u] = lo;
    }
    __syncthreads();
    FragI bh[2][4], bl[2][4];
#pragma unroll
    for (int nt = 0; nt < 2; ++nt)
#pragma unroll
        for (int kb = 0; kb < 4; ++kb) {
            bh[nt][kb].v = *(const int4*)&Bf[(nt * 4 + kb) * 256 + lane * 4];
            bl[nt][kb].v = *(const int4*)&Bf[2048 + (nt * 4 + kb) * 256 + lane * 4];
        }
#define MM(A, B, C) C = __builtin_amdgcn_mfma_f32_16x16x32_bf16(A, B, C, 0, 0, 0)
    for (int r = 0; r < 16; ++r) {
        int lt = wave + 4 * r;
        FragI ah[4], al[4];
#pragma unroll
        for (int kb = 0; kb < 4; ++kb) {
            ah[kb].v = *(const int4*)&BFhi[lt * 1024 + kb * 256 + lane * 4];
            al[kb].v = *(const int4*)&BFlo[lt * 1024 + kb * 256 + lane * 4];
        }
        f32x4 a0 = {0.f, 0.f, 0.f, 0.f}, a1 = {0.f, 0.f, 0.f, 0.f};
#pragma unroll
        for (int kb = 0; kb < 4; ++kb) {
            MM(ah[kb].s, bh[0][kb].s, a0);
            MM(ah[kb].s, bl[0][kb].s, a0);
            MM(al[kb].s, bh[0][kb].s, a0);
            MM(ah[kb].s, bh[1][kb].s, a1);
            MM(ah[kb].s, bl[1][kb].s, a1);
            MM(al[kb].s, bh[1][kb].s, a1);
        }
        int lrow = lt * 16 + (lane >> 4) * 4;
        int icol = i0 + (lane & 15);
#pragma unroll
        for (int j = 0; j < 4; ++j) {
            base[(size_t)(lrow + j) * EQ + icol]      = a0[j];
            base[(size_t)(lrow + j) * EQ + icol + 16] = a1[j];
        }
    }
#undef MM
}

extern "C" void kernel_launch(void* const* d_in, const int* in_sizes, int n_in,
                              void* d_out, int out_size, void* d_ws, size_t ws_size,
                              hipStream_t stream) {
    const float* q  = (const float*)d_in[0];
    const float* wr = (const float*)d_in[1];
    const float* wi = (const float*)d_in[2];
    float* out = (float*)d_out;
    unsigned* BFhi = (unsigned*)d_ws;           // u32 [0, 65536)
    unsigned* BFlo = BFhi + 65536;              // u32 [65536, 131072)  (512 KB ws)

    hipLaunchKernelGGL(k_trig,   dim3(256), dim3(256), 0, stream, BFhi, BFlo, out);
    hipLaunchKernelGGL(k_dft3,   dim3(512), dim3(512), 0, stream, q, out);
    hipLaunchKernelGGL(k_modes6, dim3(512), dim3(512), 0, stream, wr, wi, out);
    hipLaunchKernelGGL(k_inv3,   dim3(512), dim3(256), 0, stream, BFhi, BFlo, out);
}

// Round 9
// 143.371 us; speedup vs baseline: 1.0381x; 1.0381x over previous
//
#include <hip/hip_runtime.h>
#include <math.h>

// Problem constants
#define LQ 1024
#define EQ 512
#define BQ 32
#define MQ 64

static constexpr int BCHUNK = LQ * EQ;   // 524288 floats per b-slice of d_out
// d_out overlay (per b-slice of 524288 floats), phase by phase:
//  k_trig:   Tm bf16 A-frags in slice0 floats [0, 131072)
//  k_dft4:   reads q + Tm-frags; writes SPLITX bf16 arrays 0..3 (sx_ptr) in
//            slices z=0..7 at [z][262144, 524288)  (disjoint from Tm-frags)
//  k_modes7: Opart[hs][c][i] hs=0..3 at b*BCHUNK + hs*65536  [0,262144)
//  k_inv3:   y[l][i] overwrites slice. Each block reads ONLY its own i-columns
//            of the 4 partials (staged to LDS before any write -> WAR-safe).

typedef short short8 __attribute__((ext_vector_type(8)));
typedef float f32x4 __attribute__((ext_vector_type(4)));
typedef unsigned short ushort_t;

union FragI { int i[4]; int4 v; short8 s; };

// async global->LDS, 16B per lane; dest must be wave-uniform base (+lane*16 HW)
__device__ __forceinline__ void gload16(const float* g, float* l) {
    __builtin_amdgcn_global_load_lds(
        (const __attribute__((address_space(1))) void*)g,
        (__attribute__((address_space(3))) void*)l, 16, 0, 0);
}

// SPLITX: 4 bf16 arrays [m(64)][hblk(16)][b(32)][hh(32)], arr: 0=xrHi 1=xrLo
// 2=xiHi 3=xiLo. Flat bf16 index G = arr*2^20 + m*16384 + (h/32)*1024 + b*32
// + (h%32), mapped into 1MB-float zones: z = G>>19 at slice z offset 262144.
__device__ inline char* sx_ptr(float* dout, int arr, int m, int b, int h) {
    unsigned G = ((unsigned)arr << 20) + ((unsigned)m << 14) +
                 ((unsigned)(h >> 5) << 10) + ((unsigned)b << 5) + (unsigned)(h & 31);
    unsigned z = G >> 19, w = G & 524287u;
    return (char*)(dout + (size_t)z * BCHUNK + 262144) + (size_t)w * 2;
}

// split two fp32 into packed bf16 pairs (truncation; lo captures the residual)
__device__ inline void split2(float a, float b, unsigned& hi, unsigned& lo) {
    unsigned ua = __float_as_uint(a), ub = __float_as_uint(b);
    unsigned ha = ua & 0xFFFF0000u, hb = ub & 0xFFFF0000u;
    hi = (ua >> 16) | hb;
    float la = a - __uint_as_float(ha);
    float lb = b - __uint_as_float(hb);
    lo = (__float_as_uint(la) >> 16) | (__float_as_uint(lb) & 0xFFFF0000u);
}

__device__ inline void split1(float x, ushort_t& hi, ushort_t& lo) {
    unsigned u = __float_as_uint(x);
    hi = (ushort_t)(u >> 16);
    float r = x - __uint_as_float(u & 0xFFFF0000u);
    lo = (ushort_t)(__float_as_uint(r) >> 16);
}

// ---------------- kernel 0: trig tables (unchanged round-8) ----------------
__global__ __launch_bounds__(256) void k_trig(unsigned* __restrict__ BFhi,
                                              unsigned* __restrict__ BFlo,
                                              float* __restrict__ dout) {
    int idx = blockIdx.x * 256 + threadIdx.x;   // 0..65535 = l*64+m
    int l = idx >> 6, m = idx & 63;
    int tt = (l * m) & (LQ - 1);
    float ang = (float)tt * 6.135923151542565e-03f;  // 2*pi/1024
    float s, c;
    sincosf(ang, &s, &c);
    float coef = (m == 0 ? 1.0f : 2.0f) * (1.0f / (float)LQ);
    float b0 = coef * c;
    float b1 = (m == 0) ? 0.0f : (-2.0f / (float)LQ) * s;
    unsigned hi, lo;
    split2(b0, b1, hi, lo);
    {
        int lt = l >> 4, kb = m >> 4, kgb = (m & 15) >> 2;
        int lane = kgb * 16 + (l & 15);
        int u = lt * 1024 + kb * 256 + lane * 4 + (m & 3);
        BFhi[u] = hi;
        BFlo[u] = lo;
    }
    ushort_t* THs = (ushort_t*)dout;
    ushort_t* TLs = (ushort_t*)(dout + 65536);
    int ks = l >> 5, kg = (l >> 3) & 3, j = l & 7;
    int mt = m >> 3;
    int lane0 = kg * 16 + 2 * (m & 7);
    ushort_t ch, cl, sh, sl;
    split1(c, ch, cl);
    split1(-s, sh, sl);
    int u0 = ((ks * 8 + mt) * 64 + lane0) * 8 + j;
    THs[u0] = ch;  TLs[u0] = cl;
    THs[u0 + 8] = sh;  TLs[u0 + 8] = sl;
}

#define MM(A, B, C) C = __builtin_amdgcn_mfma_f32_16x16x32_bf16(A, B, C, 0, 0, 0)

// ---------------- kernel 1: truncated DFT via MFMA, v2 ----------------
// Per b: D[mc][h] = sum_l Tm[mc][l] * q[l][h]; M=mc(128), K=l(1024), N=h(512).
// grid 512 = b(32) x hg(16: 32 h). block 512 = 8 waves.
// q: global_load_lds into double-buffered LDS (1 barrier/chunk, pipelined).
// Tm A-frags: 8 dwordx4 hoisted to chunk top (L2-hot 512KB table).
__global__ __launch_bounds__(512, 4) void k_dft4(const float* __restrict__ q,
                                                 float* __restrict__ dout) {
    __shared__ float qs[2 * 2048];      // 16KB: [buf][lp 64][h 32]
    const int t    = threadIdx.x;
    const int wave = t >> 6;
    const int lane = t & 63;
    const int a    = wave & 3;
    const int ht   = wave >> 2;
    const int b    = blockIdx.x >> 4;
    const int hg   = blockIdx.x & 15;
    const int hbase = hg * 32;
    const int col  = lane & 15;
    const int kg   = lane >> 4;
    const float* qb = q + (size_t)b * BCHUNK;
    const int4* TH4 = (const int4*)dout;
    const int4* TL4 = (const int4*)(dout + 65536);

    f32x4 acc[2] = {{0.f, 0.f, 0.f, 0.f}, {0.f, 0.f, 0.f, 0.f}};
    const int lp = wave * 8 + (lane >> 3);     // slot row for gload src
    const int hq = 4 * (lane & 7);

    // prologue: chunk 0 into buf 0
    gload16(qb + (size_t)lp * EQ + hbase + hq, &qs[wave * 256]);

    int cur = 0;
    for (int cc = 0; cc < 16; ++cc) {
        __syncthreads();                        // q(cc) ready in buf[cur]
        // T-fragment loads, hoisted (oldest in vmcnt queue)
        FragI ah[2][2], al[2][2];
#pragma unroll
        for (int ksl = 0; ksl < 2; ++ksl)
#pragma unroll
            for (int ti = 0; ti < 2; ++ti) {
                int idx = ((cc * 2 + ksl) * 8 + 2 * a + ti) * 64 + lane;
                ah[ksl][ti].v = TH4[idx];
                al[ksl][ti].v = TL4[idx];
            }
        // prefetch next q chunk into other buffer (stays outstanding)
        if (cc < 15)
            gload16(qb + (size_t)((cc + 1) * 64 + lp) * EQ + hbase + hq,
                    &qs[(cur ^ 1) * 2048 + wave * 256]);
#pragma unroll
        for (int ksl = 0; ksl < 2; ++ksl) {
            float v[8];
#pragma unroll
            for (int j = 0; j < 8; ++j)
                v[j] = qs[cur * 2048 + (ksl * 32 + kg * 8 + j) * 32 + ht * 16 + col];
            FragI bhiF, bloF;
#pragma unroll
            for (int k2 = 0; k2 < 4; ++k2) {
                unsigned h_, l_;
                split2(v[2 * k2], v[2 * k2 + 1], h_, l_);
                bhiF.i[k2] = (int)h_;
                bloF.i[k2] = (int)l_;
            }
#pragma unroll
            for (int ti = 0; ti < 2; ++ti) {
                MM(ah[ksl][ti].s, bhiF.s, acc[ti]);
                MM(ah[ksl][ti].s, bloF.s, acc[ti]);
                MM(al[ksl][ti].s, bhiF.s, acc[ti]);
            }
        }
        cur ^= 1;
    }
    // epilogue: split accumulators into SPLITX arrays 0..3
    const int h = hbase + ht * 16 + col;
#pragma unroll
    for (int ti = 0; ti < 2; ++ti) {
        int mt = 2 * a + ti;
        int mA = mt * 8 + kg * 2;
#pragma unroll
        for (int mi = 0; mi < 2; ++mi) {
            float xr = acc[ti][2 * mi];
            float xi = acc[ti][2 * mi + 1];
            ushort_t rh, rl, ih_, il_;
            split1(xr, rh, rl);
            split1(xi, ih_, il_);
            int m = mA + mi;
            *(ushort_t*)sx_ptr(dout, 0, m, b, h) = rh;
            *(ushort_t*)sx_ptr(dout, 1, m, b, h) = rl;
            *(ushort_t*)sx_ptr(dout, 2, m, b, h) = ih_;
            *(ushort_t*)sx_ptr(dout, 3, m, b, h) = il_;
        }
    }
}

// ---------------- kernel 2: per-mode complex GEMM, v8 ----------------
// Opart[hs][b][2m+ri][i] = sum_{h in hs quarter} X[b][h][m] * W[h][i][m]
// grid 512 = hs(4) x mc(4) x it(32), no swizzle. block 512 = 8 waves.
// W: global_load_lds (8x16B/thread) with XOR-pre-swizzled source (m4^=h>>3&3)
// -> single-buffered 64KB LDS, m97-style 2-barrier chunk loop.
// X: register software pipeline, one (mi,nt) group (4 dwordx4) ahead; X groups
// issued BEFORE W gloads in queue order so waiting X never drains W.
__global__ __launch_bounds__(512, 4) void k_modes7(const float* __restrict__ wreal,
                                                   const float* __restrict__ wimag,
                                                   float* __restrict__ dout) {
    __shared__ float Wlds[16384];        // 64KB: [part2][h32][i16][m4-slot swz]
    const int t    = threadIdx.x;
    const int wave = t >> 6;
    const int lane = t & 63;
    const int blk  = blockIdx.x;
    const int hs   = blk >> 7;
    const int mc   = (blk >> 5) & 3;
    const int it   = blk & 31;
    const int i0   = it * 16;
    const int m0   = mc * 16;
    const int col  = lane & 15;
    const int kg   = lane >> 4;
    const int hbase = hs * 128;

    const char* xp0 = sx_ptr(dout, 0, m0 + 2 * wave, col, hbase + kg * 8);

    f32x4 zero4 = {0.f, 0.f, 0.f, 0.f};
    f32x4 acc[2][2][2];                  // [mi][part][nt]
#pragma unroll
    for (int a = 0; a < 2; ++a)
#pragma unroll
        for (int bq = 0; bq < 2; ++bq)
#pragma unroll
            for (int c = 0; c < 2; ++c) acc[a][bq][c] = zero4;

    FragI xA[4], xB[4];
    short8 aW[2][2];                     // [part][prec]
    short8 nW[2];                        // -Wi hi/lo

#define LDX(BUF, MI, NT, KK)                                                  \
    {                                                                         \
        const char* xpm_ = xp0 + (size_t)(MI) * 32768 +                       \
                           (size_t)(KK) * 2048 + (size_t)(NT) * 1024;         \
        BUF[0].v = *(const int4*)(xpm_);                                      \
        BUF[1].v = *(const int4*)(xpm_ + 4194304);                            \
        BUF[2].v = *(const int4*)(xpm_ + 2 * 4194304);                        \
        BUF[3].v = *(const int4*)(xpm_ + 3 * 4194304);                        \
    }

#define READW(MI)                                                             \
    {                                                                         \
        const int mloc_ = 2 * wave + (MI);                                    \
        const int mb4_ = mloc_ >> 2;                                          \
        const int mo_ = mloc_ & 3;                                            \
        _Pragma("unroll")                                                     \
        for (int part = 0; part < 2; ++part) {                                \
            float v[8];                                                       \
            _Pragma("unroll")                                                 \
            for (int j = 0; j < 8; ++j)                                       \
                v[j] = Wlds[part * 8192 + (kg * 8 + j) * 256 + col * 16 +     \
                            ((mb4_ ^ kg) << 2) + mo_];                        \
            FragI hiF, loF;                                                   \
            _Pragma("unroll")                                                 \
            for (int k2 = 0; k2 < 4; ++k2) {                                  \
                unsigned h_, l_;                                              \
                split2(v[2 * k2], v[2 * k2 + 1], h_, l_);                     \
                hiF.i[k2] = (int)h_;                                          \
                loF.i[k2] = (int)l_;                                          \
            }                                                                 \
            aW[part][0] = hiF.s;                                              \
            aW[part][1] = loF.s;                                              \
        }                                                                     \
        FragI th_, tl_, nh_, nl_;                                             \
        th_.s = aW[1][0]; tl_.s = aW[1][1];                                   \
        _Pragma("unroll")                                                     \
        for (int k2 = 0; k2 < 4; ++k2) {                                      \
            nh_.i[k2] = th_.i[k2] ^ 0x80008000;                               \
            nl_.i[k2] = tl_.i[k2] ^ 0x80008000;                               \
        }                                                                     \
        nW[0] = nh_.s;                                                        \
        nW[1] = nl_.s;                                                        \
    }

#define MMG(MI, NT, BUF)                                                      \
    MM(aW[0][0], BUF[0].s, acc[MI][0][NT]);                                   \
    MM(aW[0][0], BUF[1].s, acc[MI][0][NT]);                                   \
    MM(aW[0][1], BUF[0].s, acc[MI][0][NT]);                                   \
    MM(nW[0],    BUF[2].s, acc[MI][0][NT]);                                   \
    MM(nW[0],    BUF[3].s, acc[MI][0][NT]);                                   \
    MM(nW[1],    BUF[2].s, acc[MI][0][NT]);                                   \
    MM(aW[0][0], BUF[2].s, acc[MI][1][NT]);                                   \
    MM(aW[0][0], BUF[3].s, acc[MI][1][NT]);                                   \
    MM(aW[0][1], BUF[2].s, acc[MI][1][NT]);                                   \
    MM(aW[1][0], BUF[0].s, acc[MI][1][NT]);                                   \
    MM(aW[1][0], BUF[1].s, acc[MI][1][NT]);                                   \
    MM(aW[1][1], BUF[0].s, acc[MI][1][NT]);

    LDX(xA, 0, 0, 0);                    // first X group, oldest in queue
    for (int kk = 0; kk < 4; ++kk) {
        __syncthreads();                 // WAR: Wlds reads of kk-1 done
        // W chunk (64KB) via 8 global_load_lds per thread-slot group.
        // slot s=(r*8+wave)*64+lane -> [part][h][i][m4swz]; src pre-swizzled.
#pragma unroll
        for (int r = 0; r < 8; ++r) {
            const int W64 = r * 8 + wave;
            const int part = W64 >> 5;
            const int h = W64 & 31;
            const int hx = (h >> 3) & 3;
            const float* srcb = part ? wimag : wreal;
            const float* src = srcb +
                (size_t)(hbase + kk * 32 + h) * 32768 +
                (size_t)(i0 + (lane >> 2)) * 64 + m0 + 4 * ((lane & 3) ^ hx);
            gload16(src, &Wlds[W64 * 256]);
        }
        __syncthreads();                 // drains W (and pending X, harmless)
        // g0: (mi0,nt0) on xA
        LDX(xB, 0, 1, kk);
        READW(0);
        MMG(0, 0, xA);
        // g1: (mi0,nt1) on xB
        LDX(xA, 1, 0, kk);
        MMG(0, 1, xB);
        // g2: (mi1,nt0) on xA
        READW(1);
        LDX(xB, 1, 1, kk);
        MMG(1, 0, xA);
        // g3: (mi1,nt1) on xB
        if (kk < 3) LDX(xA, 0, 0, kk + 1);
        MMG(1, 1, xB);
    }
#undef LDX
#undef READW
#undef MMG
    // epilogue: D row = i = i0 + kg*4 + reg (contig float4), col = b
#pragma unroll
    for (int mi = 0; mi < 2; ++mi)
#pragma unroll
        for (int part = 0; part < 2; ++part)
#pragma unroll
            for (int nt = 0; nt < 2; ++nt) {
                int bb = nt * 16 + col;
                int c = 2 * (m0 + 2 * wave + mi) + part;
                f32x4 vv = acc[mi][part][nt];
                float4 o = make_float4(vv.x, vv.y, vv.z, vv.w);
                *(float4*)&dout[(size_t)bb * BCHUNK + (size_t)hs * 65536 +
                                (size_t)c * EQ + i0 + kg * 4] = o;
            }
}

// ---------------- kernel 3: truncated irfft via MFMA (unchanged) ----------
__global__ __launch_bounds__(256) void k_inv3(const unsigned* __restrict__ BFhi,
                                              const unsigned* __restrict__ BFlo,
                                              float* __restrict__ dout) {
    __shared__ unsigned Bf[4096];   // [hilo(2)][nt(2)][kb(4)][lane(64)][4] 16KB
    const int t    = threadIdx.x;
    const int wave = t >> 6;
    const int lane = t & 63;
    const int b    = blockIdx.x >> 4;
    const int it   = blockIdx.x & 15;
    const int i0   = it * 32;
    float* base = dout + (size_t)b * BCHUNK;

#pragma unroll
    for (int r = 0; r < 8; ++r) {
        int idx = r * 256 + t;               // 2048 = 64 c-pairs x 32 i
        int il = idx & 31, cp = idx >> 5;
        int c0 = 2 * cp;
        const float* p0 = base + (size_t)c0 * EQ + i0 + il;
        float s0 = p0[0] + p0[65536] + p0[2 * 65536] + p0[3 * 65536];
        const float* p1 = p0 + EQ;
        float s1 = p1[0] + p1[65536] + p1[2 * 65536] + p1[3 * 65536];
        unsigned hi, lo;
        split2(s0, s1, hi, lo);
        int nt = il >> 4, i_loc = il & 15;
        int kb = c0 >> 5, kg = (c0 & 31) >> 3, jp = (c0 & 7) >> 1;
        int u = (nt * 4 + kb) * 256 + (kg * 16 + i_loc) * 4 + jp;
        Bf[u] = hi;
        Bf[2048 + u] = lo;
    }
    __syncthreads();
    FragI bh[2][4], bl[2][4];
#pragma unroll
    for (int nt = 0; nt < 2; ++nt)
#pragma unroll
        for (int kb = 0; kb < 4; ++kb) {
            bh[nt][kb].v = *(const int4*)&Bf[(nt * 4 + kb) * 256 + lane * 4];
            bl[nt][kb].v = *(const int4*)&Bf[2048 + (nt * 4 + kb) * 256 + lane * 4];
        }
    for (int r = 0; r < 16; ++r) {
        int lt = wave + 4 * r;
        FragI ah[4], al[4];
#pragma unroll
        for (int kb = 0; kb < 4; ++kb) {
            ah[kb].v = *(const int4*)&BFhi[lt * 1024 + kb * 256 + lane * 4];
            al[kb].v = *(const int4*)&BFlo[lt * 1024 + kb * 256 + lane * 4];
        }
        f32x4 a0 = {0.f, 0.f, 0.f, 0.f}, a1 = {0.f, 0.f, 0.f, 0.f};
#pragma unroll
        for (int kb = 0; kb < 4; ++kb) {
            MM(ah[kb].s, bh[0][kb].s, a0);
            MM(ah[kb].s, bl[0][kb].s, a0);
            MM(al[kb].s, bh[0][kb].s, a0);
            MM(ah[kb].s, bh[1][kb].s, a1);
            MM(ah[kb].s, bl[1][kb].s, a1);
            MM(al[kb].s, bh[1][kb].s, a1);
        }
        int lrow = lt * 16 + (lane >> 4) * 4;
        int icol = i0 + (lane & 15);
#pragma unroll
        for (int j = 0; j < 4; ++j) {
            base[(size_t)(lrow + j) * EQ + icol]      = a0[j];
            base[(size_t)(lrow + j) * EQ + icol + 16] = a1[j];
        }
    }
}
#undef MM

extern "C" void kernel_launch(void* const* d_in, const int* in_sizes, int n_in,
                              void* d_out, int out_size, void* d_ws, size_t ws_size,
                              hipStream_t stream) {
    const float* q  = (const float*)d_in[0];
    const float* wr = (const float*)d_in[1];
    const float* wi = (const float*)d_in[2];
    float* out = (float*)d_out;
    unsigned* BFhi = (unsigned*)d_ws;           // u32 [0, 65536)
    unsigned* BFlo = BFhi + 65536;              // u32 [65536, 131072)

    hipLaunchKernelGGL(k_trig,   dim3(256), dim3(256), 0, stream, BFhi, BFlo, out);
    hipLaunchKernelGGL(k_dft4,   dim3(512), dim3(512), 0, stream, q, out);
    hipLaunchKernelGGL(k_modes7, dim3(512), dim3(512), 0, stream, wr, wi, out);
    hipLaunchKernelGGL(k_inv3,   dim3(512), dim3(256), 0, stream, BFhi, BFlo, out);
}